// Round 1
// baseline (832.864 us; speedup 1.0000x reference)
//
#include <hip/hip_runtime.h>
#include <cmath>

static constexpr int NN = 100000;   // nodes
static constexpr int NE = 2500000;  // edges (before self-loops)
static constexpr int NG = 64;       // graphs

// ---------------- degree ----------------
__global__ void deg_count_kernel(const int* __restrict__ dst, float* __restrict__ deg) {
    int i = blockIdx.x * blockDim.x + threadIdx.x;
    int stride = gridDim.x * blockDim.x;
    for (; i < NE; i += stride) atomicAdd(&deg[dst[i]], 1.0f);
}

__global__ void deg_finalize_kernel(float* __restrict__ deg) {
    int v = blockIdx.x * blockDim.x + threadIdx.x;
    if (v < NN) deg[v] = rsqrtf(deg[v] + 1.0f);  // +1 self-loop; deg>=1 always
}

// ---------------- per-layer kernels ----------------
// g[v,:] = (h[v,:] @ W) * dinv[v]; agg seeded with g (self-loop term).
template<int FIN, int FOUT>
__global__ void transform_kernel(const float* __restrict__ h, const float* __restrict__ W,
                                 const float* __restrict__ dinv,
                                 float* __restrict__ g, float* __restrict__ agg) {
    __shared__ float sW[FIN * FOUT];
    for (int i = threadIdx.x; i < FIN * FOUT; i += blockDim.x) sW[i] = W[i];
    __syncthreads();
    int idx = blockIdx.x * blockDim.x + threadIdx.x;
    int stride = gridDim.x * blockDim.x;
    const int total = NN * FOUT;
    for (; idx < total; idx += stride) {
        int v  = idx / FOUT;
        int fo = idx - v * FOUT;
        float acc = 0.0f;
#pragma unroll
        for (int fi = 0; fi < FIN; ++fi)
            acc = fmaf(h[v * FIN + fi], sW[fi * FOUT + fo], acc);
        float val = acc * dinv[v];
        g[idx]   = val;
        agg[idx] = val;   // self-loop init
    }
}

// agg[dst,f] += g[src,f] for every edge. Thread per (edge, f) with f fastest
// -> coalesced gather reads and coalesced atomic segments.
template<int F>
__global__ void scatter_kernel(const int* __restrict__ src, const int* __restrict__ dst,
                               const float* __restrict__ g, float* __restrict__ agg) {
    int idx = blockIdx.x * blockDim.x + threadIdx.x;
    int stride = gridDim.x * blockDim.x;
    const int total = NE * F;
    for (; idx < total; idx += stride) {
        int e = idx / F;          // F is a power of two -> shift
        int f = idx - e * F;
        int s = src[e];
        int d = dst[e];
        atomicAdd(&agg[d * F + f], g[s * F + f]);
    }
}

// out[v,f] = relu?(agg[v,f]*dinv[v] + b[f])   (in-place safe)
template<int F, bool RELU>
__global__ void finalize_kernel(const float* __restrict__ agg, const float* __restrict__ b,
                                const float* __restrict__ dinv, float* __restrict__ out) {
    int idx = blockIdx.x * blockDim.x + threadIdx.x;
    int stride = gridDim.x * blockDim.x;
    const int total = NN * F;
    for (; idx < total; idx += stride) {
        int v = idx / F;
        int f = idx - v * F;
        float val = agg[idx] * dinv[v] + b[f];
        if (RELU) val = fmaxf(val, 0.0f);
        out[idx] = val;
    }
}

// ---------------- pooling ----------------
__global__ void pool_kernel(const float* __restrict__ h, const int* __restrict__ batch,
                            float* __restrict__ pooled, float* __restrict__ cnt) {
    __shared__ float sp[NG * 2];
    __shared__ float sc[NG];
    for (int i = threadIdx.x; i < NG * 2; i += blockDim.x) sp[i] = 0.0f;
    for (int i = threadIdx.x; i < NG; i += blockDim.x) sc[i] = 0.0f;
    __syncthreads();
    int v = blockIdx.x * blockDim.x + threadIdx.x;
    int stride = gridDim.x * blockDim.x;
    for (; v < NN; v += stride) {
        int gi = batch[v];
        atomicAdd(&sp[gi * 2 + 0], h[v * 2 + 0]);
        atomicAdd(&sp[gi * 2 + 1], h[v * 2 + 1]);
        atomicAdd(&sc[gi], 1.0f);
    }
    __syncthreads();
    for (int i = threadIdx.x; i < NG * 2; i += blockDim.x)
        if (sp[i] != 0.0f) atomicAdd(&pooled[i], sp[i]);
    for (int i = threadIdx.x; i < NG; i += blockDim.x)
        if (sc[i] != 0.0f) atomicAdd(&cnt[i], sc[i]);
}

// ---------------- final: mean + log_softmax ----------------
__global__ void lsm_kernel(const float* __restrict__ pooled, const float* __restrict__ cnt,
                           float* __restrict__ out) {
    int gi = threadIdx.x;
    if (gi < NG) {
        float c = fmaxf(cnt[gi], 1.0f);
        float a = pooled[gi * 2 + 0] / c;
        float b = pooled[gi * 2 + 1] / c;
        float m = fmaxf(a, b);
        float lse = m + logf(expf(a - m) + expf(b - m));
        out[gi * 2 + 0] = a - lse;
        out[gi * 2 + 1] = b - lse;
    }
}

static inline int grid_for(long long total, int block) {
    long long b = (total + block - 1) / block;
    if (b > 4096) b = 4096;
    return (int)b;
}

extern "C" void kernel_launch(void* const* d_in, const int* in_sizes, int n_in,
                              void* d_out, int out_size, void* d_ws, size_t ws_size,
                              hipStream_t stream) {
    (void)in_sizes; (void)n_in; (void)out_size; (void)ws_size;

    const float* x    = (const float*)d_in[0];   // [N,3]
    const int*   ei   = (const int*)d_in[1];     // [2,E]
    const int*   bat  = (const int*)d_in[2];     // [N]
    const float* W1   = (const float*)d_in[3];
    const float* b1   = (const float*)d_in[4];
    const float* W2   = (const float*)d_in[5];
    const float* b2   = (const float*)d_in[6];
    const float* W3   = (const float*)d_in[7];
    const float* b3   = (const float*)d_in[8];
    const float* W4   = (const float*)d_in[9];
    const float* b4   = (const float*)d_in[10];
    float* out = (float*)d_out;

    const int* src = ei;        // edge_index[0]
    const int* dst = ei + NE;   // edge_index[1]

    // workspace layout (floats)
    float* ws     = (float*)d_ws;
    float* dinv   = ws;                 // N
    float* buf0   = dinv + NN;          // N*32
    float* buf1   = buf0 + NN * 32;     // N*32
    float* g      = buf1 + NN * 32;     // N*32
    float* pooled = g + NN * 32;        // NG*2
    float* cnt    = pooled + NG * 2;    // NG
    // total: N*(1+96)*4 + 768 bytes ~= 38.8 MB

    const int B = 256;

    // zero deg + pooled/cnt (poisoned by harness; must re-zero every call)
    hipMemsetAsync(dinv, 0, NN * sizeof(float), stream);
    hipMemsetAsync(pooled, 0, (NG * 3) * sizeof(float), stream);

    deg_count_kernel<<<grid_for(NE, B), B, 0, stream>>>(dst, dinv);
    deg_finalize_kernel<<<(NN + B - 1) / B, B, 0, stream>>>(dinv);

    // layer 1: 3 -> 16, relu
    transform_kernel<3, 16><<<grid_for(NN * 16, B), B, 0, stream>>>(x, W1, dinv, g, buf0);
    scatter_kernel<16><<<grid_for((long long)NE * 16, B), B, 0, stream>>>(src, dst, g, buf0);
    finalize_kernel<16, true><<<grid_for(NN * 16, B), B, 0, stream>>>(buf0, b1, dinv, buf0);

    // layer 2: 16 -> 32, relu
    transform_kernel<16, 32><<<grid_for(NN * 32, B), B, 0, stream>>>(buf0, W2, dinv, g, buf1);
    scatter_kernel<32><<<grid_for((long long)NE * 32, B), B, 0, stream>>>(src, dst, g, buf1);
    finalize_kernel<32, true><<<grid_for(NN * 32, B), B, 0, stream>>>(buf1, b2, dinv, buf1);

    // layer 3: 32 -> 16, relu
    transform_kernel<32, 16><<<grid_for(NN * 16, B), B, 0, stream>>>(buf1, W3, dinv, g, buf0);
    scatter_kernel<16><<<grid_for((long long)NE * 16, B), B, 0, stream>>>(src, dst, g, buf0);
    finalize_kernel<16, true><<<grid_for(NN * 16, B), B, 0, stream>>>(buf0, b3, dinv, buf0);

    // layer 4: 16 -> 2, no relu
    transform_kernel<16, 2><<<grid_for(NN * 2, B), B, 0, stream>>>(buf0, W4, dinv, g, buf1);
    scatter_kernel<2><<<grid_for((long long)NE * 2, B), B, 0, stream>>>(src, dst, g, buf1);
    finalize_kernel<2, false><<<grid_for(NN * 2, B), B, 0, stream>>>(buf1, b4, dinv, buf1);

    // pooling + log_softmax
    pool_kernel<<<grid_for(NN, B), B, 0, stream>>>(buf1, bat, pooled, cnt);
    lsm_kernel<<<1, 64, 0, stream>>>(pooled, cnt, out);
}

// Round 2
// 492.215 us; speedup vs baseline: 1.6921x; 1.6921x over previous
//
#include <hip/hip_runtime.h>
#include <cmath>

static constexpr int NN = 100000;   // nodes
static constexpr int NE = 2500000;  // edges (before self-loops)
static constexpr int NG = 64;       // graphs
static constexpr int NB1 = (NN + 255) / 256;  // blocks for 256-wide node pass = 391

// ---------------- degree histogram (int) ----------------
__global__ void hist_kernel(const int* __restrict__ dst, int* __restrict__ deg) {
    int i = blockIdx.x * blockDim.x + threadIdx.x;
    if (i < NE) atomicAdd(&deg[dst[i]], 1);
}

__global__ void dinv_kernel(const int* __restrict__ deg, float* __restrict__ dinv) {
    int v = blockIdx.x * blockDim.x + threadIdx.x;
    if (v < NN) dinv[v] = rsqrtf((float)deg[v] + 1.0f);  // +1 self-loop
}

// ---------------- two-level exclusive scan over deg ----------------
__global__ void scan_block_kernel(const int* __restrict__ deg, int* __restrict__ incl,
                                  int* __restrict__ bsum) {
    __shared__ int s[256];
    int t = threadIdx.x;
    int i = blockIdx.x * 256 + t;
    int v = (i < NN) ? deg[i] : 0;
    s[t] = v; __syncthreads();
#pragma unroll
    for (int off = 1; off < 256; off <<= 1) {
        int x = (t >= off) ? s[t - off] : 0;
        __syncthreads();
        s[t] += x;
        __syncthreads();
    }
    if (i < NN) incl[i] = s[t];
    if (t == 255) bsum[blockIdx.x] = s[255];
}

__global__ void scan_sums_kernel(int* __restrict__ bsum) {  // exclusive, in-place, NB1 elems
    __shared__ int s[512];
    int t = threadIdx.x;
    int orig = (t < NB1) ? bsum[t] : 0;
    s[t] = orig; __syncthreads();
#pragma unroll
    for (int off = 1; off < 512; off <<= 1) {
        int x = (t >= off) ? s[t - off] : 0;
        __syncthreads();
        s[t] += x;
        __syncthreads();
    }
    if (t < NB1) bsum[t] = s[t] - orig;
}

// row_start[i] = exclusive scan; cursor[i] = same (consumed by fill)
__global__ void finalize_rows_kernel(const int* __restrict__ incl, const int* __restrict__ deg,
                                     const int* __restrict__ boff,
                                     int* __restrict__ row_start, int* __restrict__ cursor) {
    int i = blockIdx.x * blockDim.x + threadIdx.x;
    if (i < NN) {
        int ex = incl[i] - deg[i] + boff[i >> 8];
        row_start[i] = ex;
        cursor[i] = ex;
    }
}

__global__ void csr_fill_kernel(const int* __restrict__ src, const int* __restrict__ dst,
                                int* __restrict__ cursor, int* __restrict__ csr_src) {
    int e = blockIdx.x * blockDim.x + threadIdx.x;
    if (e < NE) {
        int p = atomicAdd(&cursor[dst[e]], 1);
        csr_src[p] = src[e];
    }
}

// ---------------- scale: xs = x * dinv (width 3) ----------------
__global__ void scale3_kernel(const float* __restrict__ x, const float* __restrict__ dinv,
                              float* __restrict__ xs) {
    int idx = blockIdx.x * blockDim.x + threadIdx.x;
    if (idx < NN * 3) {
        int v = idx / 3;
        xs[idx] = x[idx] * dinv[v];
    }
}

// ---------------- pull aggregation, scalar, width F ----------------
// out[v,f] = dinv[v]*(g[v,f] + sum_{incoming e} g[src_e,f]) (+bias)(+relu)
template<int F, bool BIAS, bool RELU>
__global__ void aggS_kernel(const float* __restrict__ g, const int* __restrict__ csr,
                            const int* __restrict__ rs, const int* __restrict__ deg,
                            const float* __restrict__ dinv, const float* __restrict__ bias,
                            float* __restrict__ out) {
    int idx = blockIdx.x * blockDim.x + threadIdx.x;
    if (idx >= NN * F) return;
    int v = idx / F;
    int f = idx - v * F;
    float sum = g[idx];
    int s0 = rs[v], cnt = deg[v];
    for (int j = 0; j < cnt; ++j) {
        int s = csr[s0 + j];
        sum += g[s * F + f];
    }
    float val = sum * dinv[v];
    if (BIAS) val += bias[f];
    if (RELU) val = fmaxf(val, 0.0f);
    out[idx] = val;
}

// ---------------- pull aggregation, width 16, float4 per thread ----------------
template<bool BIAS, bool RELU>
__global__ void agg16_kernel(const float* __restrict__ g, const int* __restrict__ csr,
                             const int* __restrict__ rs, const int* __restrict__ deg,
                             const float* __restrict__ dinv, const float* __restrict__ bias,
                             float* __restrict__ out) {
    int idx = blockIdx.x * blockDim.x + threadIdx.x;
    if (idx >= NN * 4) return;
    int v = idx >> 2, q = idx & 3;
    const float4* gp = (const float4*)g;
    float4 sum = gp[v * 4 + q];
    int s0 = rs[v], cnt = deg[v];
    for (int j = 0; j < cnt; ++j) {
        int s = csr[s0 + j];
        float4 t = gp[s * 4 + q];
        sum.x += t.x; sum.y += t.y; sum.z += t.z; sum.w += t.w;
    }
    float dv = dinv[v];
    sum.x *= dv; sum.y *= dv; sum.z *= dv; sum.w *= dv;
    if (BIAS) {
        float4 bv = ((const float4*)bias)[q];
        sum.x += bv.x; sum.y += bv.y; sum.z += bv.z; sum.w += bv.w;
    }
    if (RELU) {
        sum.x = fmaxf(sum.x, 0.0f); sum.y = fmaxf(sum.y, 0.0f);
        sum.z = fmaxf(sum.z, 0.0f); sum.w = fmaxf(sum.w, 0.0f);
    }
    ((float4*)out)[v * 4 + q] = sum;
}

// ---------------- dense transform, thread per (v, fo) ----------------
template<int FIN, int FOUT, bool BIAS, bool RELU, bool SCALE>
__global__ void transform_kernel(const float* __restrict__ h, const float* __restrict__ W,
                                 const float* __restrict__ b, const float* __restrict__ dinv,
                                 float* __restrict__ out) {
    __shared__ float sW[FIN * FOUT];
    for (int i = threadIdx.x; i < FIN * FOUT; i += blockDim.x) sW[i] = W[i];
    __syncthreads();
    int idx = blockIdx.x * blockDim.x + threadIdx.x;
    if (idx >= NN * FOUT) return;
    int v = idx / FOUT;
    int fo = idx - v * FOUT;
    float acc = BIAS ? b[fo] : 0.0f;
#pragma unroll
    for (int fi = 0; fi < FIN; ++fi)
        acc = fmaf(h[v * FIN + fi], sW[fi * FOUT + fo], acc);
    if (RELU) acc = fmaxf(acc, 0.0f);
    if (SCALE) acc *= dinv[v];
    out[idx] = acc;
}

// ---------------- fused 16 -> relu(32) -> 16 transform chain, thread per node ----------------
// g3[v,:] = ( relu(a2[v,:] @ W2 + b2) @ W3 ) * dinv[v]
__global__ void fused_mid_kernel(const float* __restrict__ a2, const float* __restrict__ W2,
                                 const float* __restrict__ b2, const float* __restrict__ W3,
                                 const float* __restrict__ dinv, float* __restrict__ g3) {
    __shared__ float sW2[16 * 32];
    __shared__ float sW3[32 * 16];
    __shared__ float sb2[32];
    for (int i = threadIdx.x; i < 512; i += blockDim.x) { sW2[i] = W2[i]; sW3[i] = W3[i]; }
    for (int i = threadIdx.x; i < 32; i += blockDim.x) sb2[i] = b2[i];
    __syncthreads();
    int v = blockIdx.x * blockDim.x + threadIdx.x;
    if (v >= NN) return;
    float a[16];
    const float4* ap = (const float4*)(a2 + (size_t)v * 16);
#pragma unroll
    for (int i = 0; i < 4; ++i) {
        float4 r = ap[i];
        a[i * 4 + 0] = r.x; a[i * 4 + 1] = r.y; a[i * 4 + 2] = r.z; a[i * 4 + 3] = r.w;
    }
    float t[32];
#pragma unroll
    for (int fo = 0; fo < 32; ++fo) {
        float acc = sb2[fo];
#pragma unroll
        for (int fi = 0; fi < 16; ++fi) acc = fmaf(a[fi], sW2[fi * 32 + fo], acc);
        t[fo] = fmaxf(acc, 0.0f);
    }
    float dv = dinv[v];
    float* o = g3 + (size_t)v * 16;
#pragma unroll
    for (int fo = 0; fo < 16; ++fo) {
        float acc = 0.0f;
#pragma unroll
        for (int fi = 0; fi < 32; ++fi) acc = fmaf(t[fi], sW3[fi * 16 + fo], acc);
        o[fo] = acc * dv;
    }
}

// ---------------- pooling ----------------
__global__ void pool_kernel(const float* __restrict__ h, const int* __restrict__ batch,
                            float* __restrict__ pooled, float* __restrict__ cnt) {
    __shared__ float sp[NG * 2];
    __shared__ float sc[NG];
    for (int i = threadIdx.x; i < NG * 2; i += blockDim.x) sp[i] = 0.0f;
    for (int i = threadIdx.x; i < NG; i += blockDim.x) sc[i] = 0.0f;
    __syncthreads();
    int v = blockIdx.x * blockDim.x + threadIdx.x;
    int stride = gridDim.x * blockDim.x;
    for (; v < NN; v += stride) {
        int gi = batch[v];
        atomicAdd(&sp[gi * 2 + 0], h[v * 2 + 0]);
        atomicAdd(&sp[gi * 2 + 1], h[v * 2 + 1]);
        atomicAdd(&sc[gi], 1.0f);
    }
    __syncthreads();
    for (int i = threadIdx.x; i < NG * 2; i += blockDim.x)
        if (sp[i] != 0.0f) atomicAdd(&pooled[i], sp[i]);
    for (int i = threadIdx.x; i < NG; i += blockDim.x)
        if (sc[i] != 0.0f) atomicAdd(&cnt[i], sc[i]);
}

__global__ void lsm_kernel(const float* __restrict__ pooled, const float* __restrict__ cnt,
                           float* __restrict__ out) {
    int gi = threadIdx.x;
    if (gi < NG) {
        float c = fmaxf(cnt[gi], 1.0f);
        float a = pooled[gi * 2 + 0] / c;
        float b = pooled[gi * 2 + 1] / c;
        float m = fmaxf(a, b);
        float lse = m + logf(expf(a - m) + expf(b - m));
        out[gi * 2 + 0] = a - lse;
        out[gi * 2 + 1] = b - lse;
    }
}

extern "C" void kernel_launch(void* const* d_in, const int* in_sizes, int n_in,
                              void* d_out, int out_size, void* d_ws, size_t ws_size,
                              hipStream_t stream) {
    (void)in_sizes; (void)n_in; (void)out_size; (void)ws_size;

    const float* x   = (const float*)d_in[0];   // [N,3]
    const int*   ei  = (const int*)d_in[1];     // [2,E]
    const int*   bat = (const int*)d_in[2];     // [N]
    const float* W1  = (const float*)d_in[3];
    const float* b1  = (const float*)d_in[4];
    const float* W2  = (const float*)d_in[5];
    const float* b2  = (const float*)d_in[6];
    const float* W3  = (const float*)d_in[7];
    const float* b3  = (const float*)d_in[8];
    const float* W4  = (const float*)d_in[9];
    const float* b4  = (const float*)d_in[10];
    float* out = (float*)d_out;

    const int* src = ei;        // edge_index[0]
    const int* dst = ei + NE;   // edge_index[1]

    // ---- workspace layout ----
    char* w = (char*)d_ws;
    int*   deg_i     = (int*)w;                      w += (size_t)NN * 4;
    int*   incl      = (int*)w;                      w += (size_t)NN * 4;   // also cursor
    int*   row_start = (int*)w;                      w += (size_t)NN * 4;
    int*   cursor    = (int*)w;                      w += (size_t)NN * 4;
    int*   bsum      = (int*)w;                      w += 512 * 4;
    int*   csr_src   = (int*)w;                      w += (size_t)NE * 4;
    float* dinv      = (float*)w;                    w += (size_t)NN * 4;
    float* bufA      = (float*)w;                    w += (size_t)NN * 16 * 4;
    float* bufB      = (float*)w;                    w += (size_t)NN * 16 * 4;
    float* pooled    = (float*)w;                    w += NG * 2 * 4;
    float* cnt       = (float*)w;                    w += NG * 4;
    // total ~= 26 MB

    const int B = 256;
    const int gE = (NE + B - 1) / B;

    // zero deg + pooled/cnt (harness poisons ws)
    hipMemsetAsync(deg_i, 0, (size_t)NN * 4, stream);
    hipMemsetAsync(pooled, 0, (NG * 3) * sizeof(float), stream);

    // degree + dinv + CSR
    hist_kernel<<<gE, B, 0, stream>>>(dst, deg_i);
    dinv_kernel<<<NB1, B, 0, stream>>>(deg_i, dinv);
    scan_block_kernel<<<NB1, B, 0, stream>>>(deg_i, incl, bsum);
    scan_sums_kernel<<<1, 512, 0, stream>>>(bsum);
    finalize_rows_kernel<<<NB1, B, 0, stream>>>(incl, deg_i, bsum, row_start, cursor);
    csr_fill_kernel<<<gE, B, 0, stream>>>(src, dst, cursor, csr_src);

    // ---- layer 1 (aggregate at input width 3) ----
    // xs = x * dinv           [A, width3]
    scale3_kernel<<<(NN * 3 + B - 1) / B, B, 0, stream>>>(x, dinv, bufA);
    // a1 = dinv*(xs + sum)    [B, width3]
    aggS_kernel<3, false, false><<<(NN * 3 + B - 1) / B, B, 0, stream>>>(
        bufA, csr_src, row_start, deg_i, dinv, nullptr, bufB);
    // g2 = relu(a1@W1+b1)*dinv  [A, width16]
    transform_kernel<3, 16, true, true, true><<<(NN * 16 + B - 1) / B, B, 0, stream>>>(
        bufB, W1, b1, dinv, bufA);

    // ---- layer 2 (aggregate at input width 16) ----
    // a2 = dinv*(g2 + sum)    [B, width16]
    agg16_kernel<false, false><<<(NN * 4 + B - 1) / B, B, 0, stream>>>(
        bufA, csr_src, row_start, deg_i, dinv, nullptr, bufB);
    // g3 = (relu(a2@W2+b2)@W3)*dinv   [A, width16]  (fused layer2 epilogue + layer3 transform)
    fused_mid_kernel<<<NB1, B, 0, stream>>>(bufB, W2, b2, W3, dinv, bufA);

    // ---- layer 3 completion (aggregate at output width 16) ----
    // h3 = relu(dinv*(g3 + sum) + b3)   [B, width16]
    agg16_kernel<true, true><<<(NN * 4 + B - 1) / B, B, 0, stream>>>(
        bufA, csr_src, row_start, deg_i, dinv, b3, bufB);

    // ---- layer 4 (aggregate at output width 2) ----
    // g4 = (h3@W4)*dinv       [A, width2]
    transform_kernel<16, 2, false, false, true><<<(NN * 2 + B - 1) / B, B, 0, stream>>>(
        bufB, W4, nullptr, dinv, bufA);
    // h4 = dinv*(g4 + sum) + b4   [B, width2]
    aggS_kernel<2, true, false><<<(NN * 2 + B - 1) / B, B, 0, stream>>>(
        bufA, csr_src, row_start, deg_i, dinv, b4, bufB);

    // pooling + log_softmax
    pool_kernel<<<2048, B, 0, stream>>>(bufB, bat, pooled, cnt);
    lsm_kernel<<<1, 64, 0, stream>>>(pooled, cnt, out);
}

// Round 3
// 242.648 us; speedup vs baseline: 3.4324x; 2.0285x over previous
//
#include <hip/hip_runtime.h>
#include <cmath>

static constexpr int NN = 100000;   // nodes
static constexpr int NE = 2500000;  // edges (before self-loops)
static constexpr int NG = 64;       // graphs
static constexpr int NB1 = (NN + 255) / 256;   // 391 (also bucket count)
static constexpr int NBUCK = NB1;              // buckets = 256-node ranges
static constexpr int CAP = 8192;               // staging capacity per bucket (avg 6400, +22 sigma safe)
static constexpr int EPB = 4096;               // edges per partition block
static constexpr int NPB = (NE + EPB - 1) / EPB;  // 611

// ---------------- phase 1: bucketed partition of edges by dst>>8 ----------------
// staging record: src (17 bits) | (dst & 255) << 17
__global__ void partition_kernel(const int* __restrict__ src, const int* __restrict__ dst,
                                 int* __restrict__ bcursor, int* __restrict__ staging) {
    __shared__ int hist[NBUCK];
    __shared__ int bbase[NBUCK];
    __shared__ int lrank[NBUCK];
    int t = threadIdx.x;
    for (int i = t; i < NBUCK; i += 256) { hist[i] = 0; lrank[i] = 0; }
    __syncthreads();
    int e0 = blockIdx.x * EPB;
    int eend = min(e0 + EPB, NE);
    for (int e = e0 + t; e < eend; e += 256) atomicAdd(&hist[dst[e] >> 8], 1);
    __syncthreads();
    for (int i = t; i < NBUCK; i += 256)
        if (hist[i]) bbase[i] = atomicAdd(&bcursor[i * 16], hist[i]);  // padded counters
    __syncthreads();
    for (int e = e0 + t; e < eend; e += 256) {
        int d = dst[e];
        int b = d >> 8;
        int r = atomicAdd(&lrank[b], 1);
        staging[(b << 13) + bbase[b] + r] = src[e] | ((d & 255) << 17);
    }
}

// ---------------- phase 2: exclusive scan of bucket counts ----------------
__global__ void bucket_scan_kernel(const int* __restrict__ bcursor, int* __restrict__ bbase_g) {
    __shared__ int s[512];
    int t = threadIdx.x;
    int orig = (t < NBUCK) ? bcursor[t * 16] : 0;
    s[t] = orig; __syncthreads();
#pragma unroll
    for (int off = 1; off < 512; off <<= 1) {
        int y = (t >= off) ? s[t - off] : 0;
        __syncthreads();
        s[t] += y;
        __syncthreads();
    }
    if (t < NBUCK) bbase_g[t] = s[t] - orig;  // exclusive
}

// ---------------- phase 3: per-bucket CSR build + deg/dinv/row_start ----------------
__global__ void csr_build_kernel(const int* __restrict__ staging, const int* __restrict__ bcursor,
                                 const int* __restrict__ bbase_g,
                                 int* __restrict__ deg_i, float* __restrict__ dinv,
                                 int* __restrict__ row_start, int* __restrict__ csr_src) {
    __shared__ int hist[256];
    __shared__ int scn[256];
    __shared__ int cur[256];
    int b = blockIdx.x, t = threadIdx.x;
    int count = bcursor[b * 16];
    int base  = bbase_g[b];
    hist[t] = 0;
    __syncthreads();
    const int* st = staging + (b << 13);
    for (int i = t; i < count; i += 256) atomicAdd(&hist[st[i] >> 17], 1);
    __syncthreads();
    int h = hist[t];
    scn[t] = h; __syncthreads();
#pragma unroll
    for (int off = 1; off < 256; off <<= 1) {
        int y = (t >= off) ? scn[t - off] : 0;
        __syncthreads();
        scn[t] += y;
        __syncthreads();
    }
    int ex = scn[t] - h;  // exclusive within bucket
    int v = (b << 8) + t;
    if (v < NN) {
        deg_i[v]     = h;
        row_start[v] = base + ex;
        dinv[v]      = rsqrtf((float)h + 1.0f);  // +1 self-loop
    }
    cur[t] = ex;
    __syncthreads();
    for (int i = t; i < count; i += 256) {
        int p = st[i];
        int r = atomicAdd(&cur[p >> 17], 1);
        csr_src[base + r] = p & 0x1FFFF;
    }
}

// ---------------- scale: xs = x * dinv (width 3) ----------------
__global__ void scale3_kernel(const float* __restrict__ x, const float* __restrict__ dinv,
                              float* __restrict__ xs) {
    int idx = blockIdx.x * blockDim.x + threadIdx.x;
    if (idx < NN * 3) {
        int v = idx / 3;
        xs[idx] = x[idx] * dinv[v];
    }
}

// ---------------- pull aggregation, scalar, width F ----------------
template<int F, bool BIAS, bool RELU>
__global__ void aggS_kernel(const float* __restrict__ g, const int* __restrict__ csr,
                            const int* __restrict__ rs, const int* __restrict__ deg,
                            const float* __restrict__ dinv, const float* __restrict__ bias,
                            float* __restrict__ out) {
    int idx = blockIdx.x * blockDim.x + threadIdx.x;
    if (idx >= NN * F) return;
    int v = idx / F;
    int f = idx - v * F;
    float sum = g[idx];
    int s0 = rs[v], cnt = deg[v];
    for (int j = 0; j < cnt; ++j) {
        int s = csr[s0 + j];
        sum += g[s * F + f];
    }
    float val = sum * dinv[v];
    if (BIAS) val += bias[f];
    if (RELU) val = fmaxf(val, 0.0f);
    out[idx] = val;
}

// ---------------- pull aggregation, width 16, float4 per thread ----------------
template<bool BIAS, bool RELU>
__global__ void agg16_kernel(const float* __restrict__ g, const int* __restrict__ csr,
                             const int* __restrict__ rs, const int* __restrict__ deg,
                             const float* __restrict__ dinv, const float* __restrict__ bias,
                             float* __restrict__ out) {
    int idx = blockIdx.x * blockDim.x + threadIdx.x;
    if (idx >= NN * 4) return;
    int v = idx >> 2, q = idx & 3;
    const float4* gp = (const float4*)g;
    float4 sum = gp[v * 4 + q];
    int s0 = rs[v], cnt = deg[v];
    for (int j = 0; j < cnt; ++j) {
        int s = csr[s0 + j];
        float4 t = gp[s * 4 + q];
        sum.x += t.x; sum.y += t.y; sum.z += t.z; sum.w += t.w;
    }
    float dv = dinv[v];
    sum.x *= dv; sum.y *= dv; sum.z *= dv; sum.w *= dv;
    if (BIAS) {
        float4 bv = ((const float4*)bias)[q];
        sum.x += bv.x; sum.y += bv.y; sum.z += bv.z; sum.w += bv.w;
    }
    if (RELU) {
        sum.x = fmaxf(sum.x, 0.0f); sum.y = fmaxf(sum.y, 0.0f);
        sum.z = fmaxf(sum.z, 0.0f); sum.w = fmaxf(sum.w, 0.0f);
    }
    ((float4*)out)[v * 4 + q] = sum;
}

// ---------------- dense transform, thread per (v, fo) ----------------
template<int FIN, int FOUT, bool BIAS, bool RELU, bool SCALE>
__global__ void transform_kernel(const float* __restrict__ h, const float* __restrict__ W,
                                 const float* __restrict__ b, const float* __restrict__ dinv,
                                 float* __restrict__ out) {
    __shared__ float sW[FIN * FOUT];
    for (int i = threadIdx.x; i < FIN * FOUT; i += blockDim.x) sW[i] = W[i];
    __syncthreads();
    int idx = blockIdx.x * blockDim.x + threadIdx.x;
    if (idx >= NN * FOUT) return;
    int v = idx / FOUT;
    int fo = idx - v * FOUT;
    float acc = BIAS ? b[fo] : 0.0f;
#pragma unroll
    for (int fi = 0; fi < FIN; ++fi)
        acc = fmaf(h[v * FIN + fi], sW[fi * FOUT + fo], acc);
    if (RELU) acc = fmaxf(acc, 0.0f);
    if (SCALE) acc *= dinv[v];
    out[idx] = acc;
}

// ---------------- fused 16 -> relu(32) -> 16 transform chain, thread per node ----------------
__global__ void fused_mid_kernel(const float* __restrict__ a2, const float* __restrict__ W2,
                                 const float* __restrict__ b2, const float* __restrict__ W3,
                                 const float* __restrict__ dinv, float* __restrict__ g3) {
    __shared__ float sW2[16 * 32];
    __shared__ float sW3[32 * 16];
    __shared__ float sb2[32];
    for (int i = threadIdx.x; i < 512; i += blockDim.x) { sW2[i] = W2[i]; sW3[i] = W3[i]; }
    for (int i = threadIdx.x; i < 32; i += blockDim.x) sb2[i] = b2[i];
    __syncthreads();
    int v = blockIdx.x * blockDim.x + threadIdx.x;
    if (v >= NN) return;
    float a[16];
    const float4* ap = (const float4*)(a2 + (size_t)v * 16);
#pragma unroll
    for (int i = 0; i < 4; ++i) {
        float4 r = ap[i];
        a[i * 4 + 0] = r.x; a[i * 4 + 1] = r.y; a[i * 4 + 2] = r.z; a[i * 4 + 3] = r.w;
    }
    float t[32];
#pragma unroll
    for (int fo = 0; fo < 32; ++fo) {
        float acc = sb2[fo];
#pragma unroll
        for (int fi = 0; fi < 16; ++fi) acc = fmaf(a[fi], sW2[fi * 32 + fo], acc);
        t[fo] = fmaxf(acc, 0.0f);
    }
    float dv = dinv[v];
    float* o = g3 + (size_t)v * 16;
#pragma unroll
    for (int fo = 0; fo < 16; ++fo) {
        float acc = 0.0f;
#pragma unroll
        for (int fi = 0; fi < 32; ++fi) acc = fmaf(t[fi], sW3[fi * 16 + fo], acc);
        o[fo] = acc * dv;
    }
}

// ---------------- pooling ----------------
__global__ void pool_kernel(const float* __restrict__ h, const int* __restrict__ batch,
                            float* __restrict__ pooled, float* __restrict__ cnt) {
    __shared__ float sp[NG * 2];
    __shared__ float sc[NG];
    for (int i = threadIdx.x; i < NG * 2; i += blockDim.x) sp[i] = 0.0f;
    for (int i = threadIdx.x; i < NG; i += blockDim.x) sc[i] = 0.0f;
    __syncthreads();
    int v = blockIdx.x * blockDim.x + threadIdx.x;
    int stride = gridDim.x * blockDim.x;
    for (; v < NN; v += stride) {
        int gi = batch[v];
        atomicAdd(&sp[gi * 2 + 0], h[v * 2 + 0]);
        atomicAdd(&sp[gi * 2 + 1], h[v * 2 + 1]);
        atomicAdd(&sc[gi], 1.0f);
    }
    __syncthreads();
    for (int i = threadIdx.x; i < NG * 2; i += blockDim.x)
        if (sp[i] != 0.0f) atomicAdd(&pooled[i], sp[i]);
    for (int i = threadIdx.x; i < NG; i += blockDim.x)
        if (sc[i] != 0.0f) atomicAdd(&cnt[i], sc[i]);
}

__global__ void lsm_kernel(const float* __restrict__ pooled, const float* __restrict__ cnt,
                           float* __restrict__ out) {
    int gi = threadIdx.x;
    if (gi < NG) {
        float c = fmaxf(cnt[gi], 1.0f);
        float a = pooled[gi * 2 + 0] / c;
        float b = pooled[gi * 2 + 1] / c;
        float m = fmaxf(a, b);
        float lse = m + logf(expf(a - m) + expf(b - m));
        out[gi * 2 + 0] = a - lse;
        out[gi * 2 + 1] = b - lse;
    }
}

extern "C" void kernel_launch(void* const* d_in, const int* in_sizes, int n_in,
                              void* d_out, int out_size, void* d_ws, size_t ws_size,
                              hipStream_t stream) {
    (void)in_sizes; (void)n_in; (void)out_size; (void)ws_size;

    const float* x   = (const float*)d_in[0];   // [N,3]
    const int*   ei  = (const int*)d_in[1];     // [2,E]
    const int*   bat = (const int*)d_in[2];     // [N]
    const float* W1  = (const float*)d_in[3];
    const float* b1  = (const float*)d_in[4];
    const float* W2  = (const float*)d_in[5];
    const float* b2  = (const float*)d_in[6];
    const float* W3  = (const float*)d_in[7];
    const float* b3  = (const float*)d_in[8];
    const float* W4  = (const float*)d_in[9];
    const float* b4  = (const float*)d_in[10];
    float* out = (float*)d_out;

    const int* src = ei;        // edge_index[0]
    const int* dst = ei + NE;   // edge_index[1]

    // ---- workspace layout ----
    char* w = (char*)d_ws;
    int*   bcursor   = (int*)w;                  w += (size_t)NBUCK * 16 * 4;   // padded counters
    int*   bbase_g   = (int*)w;                  w += 512 * 4;
    int*   staging   = (int*)w;                  w += (size_t)NBUCK * CAP * 4;  // 12.8 MB
    int*   csr_src   = (int*)w;                  w += (size_t)NE * 4;           // 10 MB
    int*   deg_i     = (int*)w;                  w += (size_t)NN * 4;
    int*   row_start = (int*)w;                  w += (size_t)NN * 4;
    float* dinv      = (float*)w;                w += (size_t)NN * 4;
    float* bufA      = (float*)w;                w += (size_t)NN * 16 * 4;
    float* bufB      = (float*)w;                w += (size_t)NN * 16 * 4;
    float* pooled    = (float*)w;                w += NG * 2 * 4;
    float* cnt       = (float*)w;                w += NG * 4;
    // total ~= 37 MB

    const int B = 256;

    // zero bucket cursors + pooled/cnt (harness poisons ws)
    hipMemsetAsync(bcursor, 0, (size_t)NBUCK * 16 * 4, stream);
    hipMemsetAsync(pooled, 0, (NG * 3) * sizeof(float), stream);

    // CSR build: partition -> scan -> per-bucket build (deg/dinv/row_start fused)
    partition_kernel<<<NPB, B, 0, stream>>>(src, dst, bcursor, staging);
    bucket_scan_kernel<<<1, 512, 0, stream>>>(bcursor, bbase_g);
    csr_build_kernel<<<NBUCK, B, 0, stream>>>(staging, bcursor, bbase_g,
                                              deg_i, dinv, row_start, csr_src);

    // ---- layer 1 (aggregate at input width 3) ----
    scale3_kernel<<<(NN * 3 + B - 1) / B, B, 0, stream>>>(x, dinv, bufA);
    aggS_kernel<3, false, false><<<(NN * 3 + B - 1) / B, B, 0, stream>>>(
        bufA, csr_src, row_start, deg_i, dinv, nullptr, bufB);
    transform_kernel<3, 16, true, true, true><<<(NN * 16 + B - 1) / B, B, 0, stream>>>(
        bufB, W1, b1, dinv, bufA);

    // ---- layer 2 (aggregate at input width 16) ----
    agg16_kernel<false, false><<<(NN * 4 + B - 1) / B, B, 0, stream>>>(
        bufA, csr_src, row_start, deg_i, dinv, nullptr, bufB);
    fused_mid_kernel<<<NB1, B, 0, stream>>>(bufB, W2, b2, W3, dinv, bufA);

    // ---- layer 3 completion (aggregate at output width 16) ----
    agg16_kernel<true, true><<<(NN * 4 + B - 1) / B, B, 0, stream>>>(
        bufA, csr_src, row_start, deg_i, dinv, b3, bufB);

    // ---- layer 4 (aggregate at output width 2) ----
    transform_kernel<16, 2, false, false, true><<<(NN * 2 + B - 1) / B, B, 0, stream>>>(
        bufB, W4, nullptr, dinv, bufA);
    aggS_kernel<2, true, false><<<(NN * 2 + B - 1) / B, B, 0, stream>>>(
        bufA, csr_src, row_start, deg_i, dinv, b4, bufB);

    // pooling + log_softmax
    pool_kernel<<<2048, B, 0, stream>>>(bufB, bat, pooled, cnt);
    lsm_kernel<<<1, 64, 0, stream>>>(pooled, cnt, out);
}